// Round 5
// baseline (187.367 us; speedup 1.0000x reference)
//
#include <hip/hip_runtime.h>
#include <hip/hip_bf16.h>
#include <math.h>

#define D_MODEL 512
#define D_FF    2048
#define NBATCH  2
#define NSEQ    384
#define NROWS   (NBATCH * NSEQ)
#define LN_EPS  1e-6f

typedef __attribute__((ext_vector_type(8))) short short8;
typedef __attribute__((ext_vector_type(4))) short short4v;
typedef __attribute__((ext_vector_type(4))) float f32x4;
typedef __hip_bfloat16 bf16;

static __device__ __forceinline__ short bfb(float x) {
    bf16 h = __float2bfloat16(x);
    return *reinterpret_cast<short*>(&h);
}

// ---------------------------------------------------------------------------
// Kernel 1: all six weight transposes fused. W[K][N] f32 -> Wt[N][K] bf16.
// ---------------------------------------------------------------------------
__global__ __launch_bounds__(256) void wt_all_kernel(
    const float* __restrict__ Wq, const float* __restrict__ Wk,
    const float* __restrict__ Wv, const float* __restrict__ Wo,
    const float* __restrict__ W1, const float* __restrict__ W2,
    bf16* __restrict__ wqt, bf16* __restrict__ wkt, bf16* __restrict__ wvt,
    bf16* __restrict__ wot, bf16* __restrict__ w1t, bf16* __restrict__ w2t)
{
    int t = blockIdx.x;
    const float* W; bf16* Wt; int K, N, bx, by;
    if (t < 1024) {
        int w = t >> 8, rem = t & 255;
        W  = (w == 0) ? Wq  : (w == 1) ? Wk  : (w == 2) ? Wv  : Wo;
        Wt = (w == 0) ? wqt : (w == 1) ? wkt : (w == 2) ? wvt : wot;
        K = 512; N = 512; bx = rem & 15; by = rem >> 4;
    } else if (t < 2048) {
        int rem = t - 1024;
        W = W1; Wt = w1t; K = 512; N = 2048; bx = rem & 63; by = rem >> 6;
    } else {
        int rem = t - 2048;
        W = W2; Wt = w2t; K = 2048; N = 512; bx = rem & 15; by = rem >> 4;
    }

    __shared__ float tile[32][33];
    int tx = threadIdx.x & 31, ty = threadIdx.x >> 5;
    #pragma unroll
    for (int r = ty; r < 32; r += 8)
        tile[r][tx] = W[(size_t)(by * 32 + r) * N + bx * 32 + tx];
    __syncthreads();
    #pragma unroll
    for (int r = ty; r < 32; r += 8)
        Wt[(size_t)(bx * 32 + r) * K + by * 32 + tx] = __float2bfloat16(tile[tx][r]);
}

// ---------------------------------------------------------------------------
// Kernel 2: x0[row,d] = emb[tokens[row], d]*sqrt(D) + PE(n,d); f32 + bf16 copy
// ---------------------------------------------------------------------------
__global__ __launch_bounds__(256) void embed_pe_kernel(
    const int* __restrict__ tokens, const float* __restrict__ emb,
    float* __restrict__ x, bf16* __restrict__ xb)
{
    int row = blockIdx.x;            // b*NSEQ + n
    int n   = row % NSEQ;
    int tok = tokens[row];
    const float sqrtD = 22.627416997969522f; // sqrt(512)
    for (int d = threadIdx.x; d < D_MODEL; d += 256) {
        float e = emb[tok * D_MODEL + d] * sqrtD;
        int   i2   = d & ~1;
        float expo = (float)i2 / (float)D_MODEL;
        float ang  = (float)n * powf(10000.0f, -expo);
        float pe   = (d & 1) ? cosf(ang) : sinf(ang);
        float val  = e + pe;
        x [(size_t)row * D_MODEL + d] = val;
        xb[(size_t)row * D_MODEL + d] = __float2bfloat16(val);
    }
}

// ---------------------------------------------------------------------------
// Kernel 3: fused QKV MFMA GEMM (no LDS). blockIdx.z selects q/k/v.
//  z=0: aexp = exp(2*(x@Wq+bq))   f32
//  z=1: bexp = exp(2*(x@Wk+bk))   f32
//  z=2: vT[b][d][j] = bf16(x@Wv+bv)   (transposed for PV MFMA B-operand)
// ---------------------------------------------------------------------------
__global__ __launch_bounds__(256) void qkv_mfma_kernel(
    const bf16* __restrict__ A,
    const bf16* __restrict__ wqt, const bf16* __restrict__ wkt, const bf16* __restrict__ wvt,
    const float* __restrict__ bq, const float* __restrict__ bk, const float* __restrict__ bv,
    float* __restrict__ aexp, float* __restrict__ bexp, bf16* __restrict__ vT)
{
    int z = blockIdx.z;
    const bf16*  Wt   = (z == 0) ? wqt : (z == 1) ? wkt : wvt;
    const float* bias = (z == 0) ? bq  : (z == 1) ? bk  : bv;

    int lane = threadIdx.x & 63, wid = threadIdx.x >> 6;
    int rowBase = blockIdx.y * 32 + (wid >> 1) * 16;
    int colBase = blockIdx.x * 64 + (wid & 1) * 32;

    const bf16* Ap  = A  + (size_t)(rowBase + (lane & 15)) * D_MODEL + ((lane >> 4) << 3);
    const bf16* Bp0 = Wt + (size_t)(colBase + (lane & 15)) * D_MODEL + ((lane >> 4) << 3);
    const bf16* Bp1 = Bp0 + (size_t)16 * D_MODEL;

    f32x4 acc0 = {0.f, 0.f, 0.f, 0.f};
    f32x4 acc1 = {0.f, 0.f, 0.f, 0.f};

    #pragma unroll 4
    for (int k0 = 0; k0 < D_MODEL; k0 += 32) {
        short8 a  = *reinterpret_cast<const short8*>(Ap  + k0);
        short8 b0 = *reinterpret_cast<const short8*>(Bp0 + k0);
        short8 b1 = *reinterpret_cast<const short8*>(Bp1 + k0);
        acc0 = __builtin_amdgcn_mfma_f32_16x16x32_bf16(a, b0, acc0, 0, 0, 0);
        acc1 = __builtin_amdgcn_mfma_f32_16x16x32_bf16(a, b1, acc1, 0, 0, 0);
    }

    int crow = rowBase + ((lane >> 4) << 2);   // rows crow..crow+3
    int ccol = colBase + (lane & 15);          // cols ccol, ccol+16

    if (z < 2) {
        float* C = (z == 0) ? aexp : bexp;
        #pragma unroll
        for (int r = 0; r < 4; ++r) {
            int row = crow + r;
            #pragma unroll
            for (int j = 0; j < 2; ++j) {
                int col = ccol + j * 16;
                float val = (j == 0 ? acc0[r] : acc1[r]) + bias[col];
                C[(size_t)row * D_MODEL + col] = __expf(2.0f * val);
            }
        }
    } else {
        int bb = crow / NSEQ;                  // batch (crow..crow+3 same batch)
        int jr = crow - bb * NSEQ;
        #pragma unroll
        for (int j = 0; j < 2; ++j) {
            int col = ccol + j * 16;
            short4v pk;
            #pragma unroll
            for (int r = 0; r < 4; ++r)
                pk[r] = bfb((j == 0 ? acc0[r] : acc1[r]) + bias[col]);
            size_t idx = ((size_t)bb * D_MODEL + col) * NSEQ + jr;
            *reinterpret_cast<short4v*>((short*)vT + idx) = pk;
        }
    }
}

// ---------------------------------------------------------------------------
// Kernel 4: additive-attention unnormalized weights.
// E[i][j] = exp( -2 * sum_d scale_d * rcp(a_id*b_jd + 1) )   (row-const cancels,
// |u|<=41 so no max needed).  Sp[i][half] = partial sum over the j-half.
// grid (NROWS/2, 2); 512 thr (8 waves).
// Lane l: jj = l&7 (j within octet), dd = l>>3 (d-slice).
// Wave w handles octets {w, w+8, w+16} of its j-half, for both i-rows.
// ---------------------------------------------------------------------------
__global__ __launch_bounds__(512) void score_kernel(
    const float* __restrict__ aexp, const float* __restrict__ bexp,
    const float* __restrict__ scale, bf16* __restrict__ E,
    float* __restrict__ Sp)
{
    int ip   = blockIdx.x;         // i-pair index
    int half = blockIdx.y;         // j-half
    int row0 = ip * 2;
    int b    = row0 / NSEQ;
    int tid  = threadIdx.x;
    int lane = tid & 63, wid = tid >> 6;
    int jj = lane & 7, dd = lane >> 3;

    const float* a0p = aexp + (size_t)row0 * D_MODEL;
    const float* a1p = a0p + D_MODEL;
    const float* bb  = bexp + (size_t)b * NSEQ * D_MODEL;

    // j columns this wave handles: j = half*192 + (wid + o*8)*8 + jj
    int jbase = half * 192 + wid * 8 + jj;

    float acc[3][2] = {};   // [octet][i-row]

    #pragma unroll
    for (int chunk = 0; chunk < 8; ++chunk) {
        int doff = chunk * 64 + dd * 8;
        float4 a0A = *(const float4*)(a0p + doff);
        float4 a0B = *(const float4*)(a0p + doff + 4);
        float4 a1A = *(const float4*)(a1p + doff);
        float4 a1B = *(const float4*)(a1p + doff + 4);
        float4 sA  = *(const float4*)(scale + doff);
        float4 sB  = *(const float4*)(scale + doff + 4);
        float a0[8] = {a0A.x,a0A.y,a0A.z,a0A.w,a0B.x,a0B.y,a0B.z,a0B.w};
        float a1[8] = {a1A.x,a1A.y,a1A.z,a1A.w,a1B.x,a1B.y,a1B.z,a1B.w};
        float sv[8] = {sA.x,sA.y,sA.z,sA.w,sB.x,sB.y,sB.z,sB.w};

        #pragma unroll
        for (int o = 0; o < 3; ++o) {
            const float* bp = bb + (size_t)(jbase + o * 64) * D_MODEL + doff;
            float4 b0 = *(const float4*)(bp);
            float4 b1 = *(const float4*)(bp + 4);
            float bv8[8] = {b0.x,b0.y,b0.z,b0.w,b1.x,b1.y,b1.z,b1.w};
            float t0 = acc[o][0], t1 = acc[o][1];
            #pragma unroll
            for (int u = 0; u < 8; ++u) {
                float r0 = __builtin_amdgcn_rcpf(fmaf(a0[u], bv8[u], 1.0f));
                float r1 = __builtin_amdgcn_rcpf(fmaf(a1[u], bv8[u], 1.0f));
                t0 = fmaf(sv[u], r0, t0);
                t1 = fmaf(sv[u], r1, t1);
            }
            acc[o][0] = t0; acc[o][1] = t1;
        }
    }

    // reduce across dd (3 stages), exp, write E, accumulate per-lane e-sums
    __shared__ float sred[8][2];
    float es0 = 0.0f, es1 = 0.0f;
    #pragma unroll
    for (int o = 0; o < 3; ++o) {
        int j = jbase + o * 64;
        float t0 = acc[o][0], t1 = acc[o][1];
        #pragma unroll
        for (int off = 8; off < 64; off <<= 1) {
            t0 += __shfl_xor(t0, off, 64);
            t1 += __shfl_xor(t1, off, 64);
        }
        float e0 = __expf(-2.0f * t0);
        float e1 = __expf(-2.0f * t1);
        if (dd == 0) {
            E[(size_t)row0 * NSEQ + j]       = __float2bfloat16(e0);
            E[(size_t)(row0+1) * NSEQ + j]   = __float2bfloat16(e1);
        }
        es0 += e0; es1 += e1;
    }
    // full-wave reduce of e-sums (each j counted 8x -> scale by 1/8)
    #pragma unroll
    for (int off = 1; off < 64; off <<= 1) {
        es0 += __shfl_xor(es0, off, 64);
        es1 += __shfl_xor(es1, off, 64);
    }
    if (lane == 0) { sred[wid][0] = es0 * 0.125f; sred[wid][1] = es1 * 0.125f; }
    __syncthreads();
    if (tid < 2) {
        float s = 0.0f;
        #pragma unroll
        for (int w = 0; w < 8; ++w) s += sred[w][tid];
        Sp[(size_t)(row0 + tid) * 2 + half] = s;
    }
}

// ---------------------------------------------------------------------------
// Kernel 5: PV MFMA + normalize: attnb[b,i,d] = (sum_j E[b,i,j] v[b,j,d]) / S_i
// ---------------------------------------------------------------------------
__global__ __launch_bounds__(256) void pv_mfma_kernel(
    const bf16* __restrict__ E, const bf16* __restrict__ vT,
    const float* __restrict__ Sp, bf16* __restrict__ attnb)
{
    int z = blockIdx.z;
    int lane = threadIdx.x & 63, wid = threadIdx.x >> 6;
    int rowBase = blockIdx.y * 32 + (wid >> 1) * 16;
    int colBase = blockIdx.x * 64 + (wid & 1) * 32;

    const bf16* Ap  = E  + ((size_t)z * NSEQ + rowBase + (lane & 15)) * NSEQ + ((lane >> 4) << 3);
    const bf16* Bp0 = vT + ((size_t)z * D_MODEL + colBase + (lane & 15)) * NSEQ + ((lane >> 4) << 3);
    const bf16* Bp1 = Bp0 + (size_t)16 * NSEQ;

    f32x4 acc0 = {0.f, 0.f, 0.f, 0.f};
    f32x4 acc1 = {0.f, 0.f, 0.f, 0.f};

    #pragma unroll 4
    for (int k0 = 0; k0 < NSEQ; k0 += 32) {
        short8 a  = *reinterpret_cast<const short8*>(Ap  + k0);
        short8 b0 = *reinterpret_cast<const short8*>(Bp0 + k0);
        short8 b1 = *reinterpret_cast<const short8*>(Bp1 + k0);
        acc0 = __builtin_amdgcn_mfma_f32_16x16x32_bf16(a, b0, acc0, 0, 0, 0);
        acc1 = __builtin_amdgcn_mfma_f32_16x16x32_bf16(a, b1, acc1, 0, 0, 0);
    }

    int crow = rowBase + ((lane >> 4) << 2);
    int ccol = colBase + (lane & 15);
    #pragma unroll
    for (int r = 0; r < 4; ++r) {
        int grow = z * NSEQ + crow + r;
        float Sinv = 1.0f / (Sp[(size_t)grow * 2] + Sp[(size_t)grow * 2 + 1]);
        #pragma unroll
        for (int j = 0; j < 2; ++j)
            attnb[(size_t)grow * D_MODEL + ccol + j * 16] =
                __float2bfloat16((j == 0 ? acc0[r] : acc1[r]) * Sinv);
    }
}

// ---------------------------------------------------------------------------
// Kernel 6: generic bf16 MFMA GEMM (no LDS): C = A @ Wt^T + bias (+resid)(+relu)
// ---------------------------------------------------------------------------
__global__ __launch_bounds__(256) void mfma_gemm_kernel(
    const bf16* __restrict__ A, const bf16* __restrict__ Wt,
    const float* __restrict__ bias, const float* __restrict__ resid,
    float* __restrict__ Cf, bf16* __restrict__ Cb,
    int K, int N, int relu)
{
    int lane = threadIdx.x & 63, wid = threadIdx.x >> 6;
    int rowBase = blockIdx.y * 32 + (wid >> 1) * 16;
    int colBase = blockIdx.x * 64 + (wid & 1) * 32;

    const bf16* Ap  = A  + (size_t)(rowBase + (lane & 15)) * K + ((lane >> 4) << 3);
    const bf16* Bp0 = Wt + (size_t)(colBase + (lane & 15)) * K + ((lane >> 4) << 3);
    const bf16* Bp1 = Bp0 + (size_t)16 * K;

    f32x4 acc0 = {0.f, 0.f, 0.f, 0.f};
    f32x4 acc1 = {0.f, 0.f, 0.f, 0.f};

    #pragma unroll 4
    for (int k0 = 0; k0 < K; k0 += 32) {
        short8 a  = *reinterpret_cast<const short8*>(Ap  + k0);
        short8 b0 = *reinterpret_cast<const short8*>(Bp0 + k0);
        short8 b1 = *reinterpret_cast<const short8*>(Bp1 + k0);
        acc0 = __builtin_amdgcn_mfma_f32_16x16x32_bf16(a, b0, acc0, 0, 0, 0);
        acc1 = __builtin_amdgcn_mfma_f32_16x16x32_bf16(a, b1, acc1, 0, 0, 0);
    }

    int crow = rowBase + ((lane >> 4) << 2);
    int ccol = colBase + (lane & 15);
    #pragma unroll
    for (int r = 0; r < 4; ++r) {
        int row = crow + r;
        #pragma unroll
        for (int j = 0; j < 2; ++j) {
            int col = ccol + j * 16;
            float val = (j == 0 ? acc0[r] : acc1[r]) + bias[col];
            if (resid) val += resid[(size_t)row * N + col];
            if (relu)  val = fmaxf(val, 0.0f);
            if (Cf) Cf[(size_t)row * N + col] = val;
            if (Cb) Cb[(size_t)row * N + col] = __float2bfloat16(val);
        }
    }
}

// ---------------------------------------------------------------------------
// Kernel 7: LayerNorm over last dim (512); optional bf16 shadow output
// ---------------------------------------------------------------------------
__global__ __launch_bounds__(256) void ln_kernel(
    const float* __restrict__ in, const float* __restrict__ gamma,
    const float* __restrict__ beta, float* __restrict__ out,
    bf16* __restrict__ outb)
{
    int row = blockIdx.x;
    int tid = threadIdx.x;
    int lane = tid & 63, wid = tid >> 6;
    __shared__ float red[4];

    float v0 = in[(size_t)row * D_MODEL + tid];
    float v1 = in[(size_t)row * D_MODEL + tid + 256];

    float s = v0 + v1;
    #pragma unroll
    for (int off = 32; off; off >>= 1) s += __shfl_xor(s, off, 64);
    if (lane == 0) red[wid] = s;
    __syncthreads();
    if (tid == 0) red[0] = red[0] + red[1] + red[2] + red[3];
    __syncthreads();
    float mu = red[0] * (1.0f / D_MODEL);
    __syncthreads();

    float d0 = v0 - mu, d1 = v1 - mu;
    float s2 = d0 * d0 + d1 * d1;
    #pragma unroll
    for (int off = 32; off; off >>= 1) s2 += __shfl_xor(s2, off, 64);
    if (lane == 0) red[wid] = s2;
    __syncthreads();
    if (tid == 0) red[0] = red[0] + red[1] + red[2] + red[3];
    __syncthreads();
    float var = red[0] * (1.0f / D_MODEL);
    float inv = rsqrtf(var + LN_EPS);

    float o0 = d0 * inv * gamma[tid] + beta[tid];
    float o1 = d1 * inv * gamma[tid + 256] + beta[tid + 256];
    out[(size_t)row * D_MODEL + tid]       = o0;
    out[(size_t)row * D_MODEL + tid + 256] = o1;
    if (outb) {
        outb[(size_t)row * D_MODEL + tid]       = __float2bfloat16(o0);
        outb[(size_t)row * D_MODEL + tid + 256] = __float2bfloat16(o1);
    }
}

// ---------------------------------------------------------------------------
extern "C" void kernel_launch(void* const* d_in, const int* in_sizes, int n_in,
                              void* d_out, int out_size, void* d_ws, size_t ws_size,
                              hipStream_t stream)
{
    const int*   tokens = (const int*)  d_in[0];
    const float* emb    = (const float*)d_in[1];
    const float* Wq     = (const float*)d_in[2];
    const float* bq     = (const float*)d_in[3];
    const float* Wk     = (const float*)d_in[4];
    const float* bk     = (const float*)d_in[5];
    const float* Wv     = (const float*)d_in[6];
    const float* bv     = (const float*)d_in[7];
    const float* ascale = (const float*)d_in[8];
    const float* Wo     = (const float*)d_in[9];
    const float* bo     = (const float*)d_in[10];
    const float* g1     = (const float*)d_in[11];
    const float* beta1  = (const float*)d_in[12];
    const float* W1     = (const float*)d_in[13];
    const float* bf1    = (const float*)d_in[14];
    const float* W2     = (const float*)d_in[15];
    const float* bf2    = (const float*)d_in[16];
    const float* g2     = (const float*)d_in[17];
    const float* beta2  = (const float*)d_in[18];

    float* out = (float*)d_out;
    float* ws  = (float*)d_ws;

    const size_t SZ = (size_t)NROWS * D_MODEL;   // 393216

    float* x0   = ws;            // live until Wo residual
    float* aexp = ws + 1 * SZ;   // exp(2q); dead after score -> reuse as t1
    float* bexp = ws + 2 * SZ;   // exp(2k); dead after score -> reuse as x1
    float* t1 = aexp;
    float* x1 = bexp;
    float* y  = x0;              // x0 dead after Wo

    bf16* x0b   = (bf16*)(ws + 3 * SZ);
    bf16* attnb = x0b + SZ;
    bf16* x1b   = attnb + SZ;
    bf16* hb    = x1b + SZ;                          // NROWS * D_FF
    bf16* Eb    = hb + (size_t)NROWS * D_FF;         // 2*384*384
    bf16* vTb   = Eb + (size_t)NBATCH * NSEQ * NSEQ; // 2*512*384
    bf16* wqt   = vTb + (size_t)NBATCH * D_MODEL * NSEQ;
    bf16* wkt   = wqt + (size_t)D_MODEL * D_MODEL;
    bf16* wvt   = wkt + (size_t)D_MODEL * D_MODEL;
    bf16* wot   = wvt + (size_t)D_MODEL * D_MODEL;
    bf16* w1t   = wot + (size_t)D_MODEL * D_MODEL;   // [D_FF][D_MODEL]
    bf16* w2t   = w1t + (size_t)D_MODEL * D_FF;      // [D_MODEL][D_FF]
    float* Sp   = (float*)(w2t + (size_t)D_FF * D_MODEL);  // [NROWS][2]

    // 1. all weight transposes (one dispatch)
    wt_all_kernel<<<3072, 256, 0, stream>>>(Wq, Wk, Wv, Wo, W1, W2,
                                            wqt, wkt, wvt, wot, w1t, w2t);

    // 2. embedding + positional encoding
    embed_pe_kernel<<<NROWS, 256, 0, stream>>>(tokens, emb, x0, x0b);

    // 3. fused QKV (z: 0->aexp, 1->bexp, 2->vT bf16)
    qkv_mfma_kernel<<<dim3(D_MODEL / 64, NROWS / 32, 3), 256, 0, stream>>>(
        x0b, wqt, wkt, wvt, bq, bk, bv, aexp, bexp, vTb);

    // 4. unnormalized attention weights E + partial row-sums Sp
    score_kernel<<<dim3(NROWS / 2, 2), 512, 0, stream>>>(aexp, bexp, ascale, Eb, Sp);

    // 5. PV + normalize -> attnb bf16
    pv_mfma_kernel<<<dim3(D_MODEL / 64, NSEQ / 32, NBATCH), 256, 0, stream>>>(
        Eb, vTb, Sp, attnb);

    // 6. output projection + residual -> t1 f32
    mfma_gemm_kernel<<<dim3(D_MODEL / 64, NROWS / 32), 256, 0, stream>>>(
        attnb, wot, bo, x0, t1, nullptr, D_MODEL, D_MODEL, 0);

    // 7. LayerNorm 1 -> x1 f32 + x1b bf16
    ln_kernel<<<NROWS, 256, 0, stream>>>(t1, g1, beta1, x1, x1b);

    // 8. FF up + ReLU -> hb bf16
    mfma_gemm_kernel<<<dim3(D_FF / 64, NROWS / 32), 256, 0, stream>>>(
        x1b, w1t, bf1, nullptr, nullptr, hb, D_MODEL, D_FF, 1);

    // 9. FF down + residual -> y f32
    mfma_gemm_kernel<<<dim3(D_MODEL / 64, NROWS / 32), 256, 0, stream>>>(
        hb, w2t, bf2, x1, y, nullptr, D_FF, D_MODEL, 0);

    // 10. LayerNorm 2 -> out
    ln_kernel<<<NROWS, 256, 0, stream>>>(y, g2, beta2, out, nullptr);
}

// Round 6
// 129.881 us; speedup vs baseline: 1.4426x; 1.4426x over previous
//
#include <hip/hip_runtime.h>
#include <hip/hip_bf16.h>
#include <math.h>

#define D_MODEL 512
#define D_FF    2048
#define NBATCH  2
#define NSEQ    384
#define NROWS   (NBATCH * NSEQ)
#define LN_EPS  1e-6f

typedef __attribute__((ext_vector_type(8))) short short8;
typedef __attribute__((ext_vector_type(4))) short short4v;
typedef __attribute__((ext_vector_type(4))) float f32x4;
typedef __hip_bfloat16 bf16;

static __device__ __forceinline__ short bfb(float x) {
    bf16 h = __float2bfloat16(x);
    return *reinterpret_cast<short*>(&h);
}

// ---------------------------------------------------------------------------
// Kernel 1: all six weight transposes fused. W[K][N] f32 -> Wt[N][K] bf16.
// ---------------------------------------------------------------------------
__global__ __launch_bounds__(256) void wt_all_kernel(
    const float* __restrict__ Wq, const float* __restrict__ Wk,
    const float* __restrict__ Wv, const float* __restrict__ Wo,
    const float* __restrict__ W1, const float* __restrict__ W2,
    bf16* __restrict__ wqt, bf16* __restrict__ wkt, bf16* __restrict__ wvt,
    bf16* __restrict__ wot, bf16* __restrict__ w1t, bf16* __restrict__ w2t)
{
    int t = blockIdx.x;
    const float* W; bf16* Wt; int K, N, bx, by;
    if (t < 1024) {
        int w = t >> 8, rem = t & 255;
        W  = (w == 0) ? Wq  : (w == 1) ? Wk  : (w == 2) ? Wv  : Wo;
        Wt = (w == 0) ? wqt : (w == 1) ? wkt : (w == 2) ? wvt : wot;
        K = 512; N = 512; bx = rem & 15; by = rem >> 4;
    } else if (t < 2048) {
        int rem = t - 1024;
        W = W1; Wt = w1t; K = 512; N = 2048; bx = rem & 63; by = rem >> 6;
    } else {
        int rem = t - 2048;
        W = W2; Wt = w2t; K = 2048; N = 512; bx = rem & 15; by = rem >> 4;
    }

    __shared__ float tile[32][33];
    int tx = threadIdx.x & 31, ty = threadIdx.x >> 5;
    #pragma unroll
    for (int r = ty; r < 32; r += 8)
        tile[r][tx] = W[(size_t)(by * 32 + r) * N + bx * 32 + tx];
    __syncthreads();
    #pragma unroll
    for (int r = ty; r < 32; r += 8)
        Wt[(size_t)(bx * 32 + r) * K + by * 32 + tx] = __float2bfloat16(tile[tx][r]);
}

// ---------------------------------------------------------------------------
// Kernel 2: x0[row,d] = emb[tokens[row], d]*sqrt(D) + PE(n,d); f32 + bf16 copy
// ---------------------------------------------------------------------------
__global__ __launch_bounds__(256) void embed_pe_kernel(
    const int* __restrict__ tokens, const float* __restrict__ emb,
    float* __restrict__ x, bf16* __restrict__ xb)
{
    int row = blockIdx.x;            // b*NSEQ + n
    int n   = row % NSEQ;
    int tok = tokens[row];
    const float sqrtD = 22.627416997969522f; // sqrt(512)
    for (int d = threadIdx.x; d < D_MODEL; d += 256) {
        float e = emb[tok * D_MODEL + d] * sqrtD;
        int   i2   = d & ~1;
        float expo = (float)i2 / (float)D_MODEL;
        float ang  = (float)n * powf(10000.0f, -expo);
        float pe   = (d & 1) ? cosf(ang) : sinf(ang);
        float val  = e + pe;
        x [(size_t)row * D_MODEL + d] = val;
        xb[(size_t)row * D_MODEL + d] = __float2bfloat16(val);
    }
}

// ---------------------------------------------------------------------------
// Kernel 3: fused QKV MFMA GEMM (no LDS). blockIdx.z selects q/k/v.
//  z=0: aexp = exp(2*(x@Wq+bq))   f32
//  z=1: bexp = exp(2*(x@Wk+bk))   f32
//  z=2: vT[b][d][j] = bf16(x@Wv+bv)   (transposed for PV MFMA B-operand)
// ---------------------------------------------------------------------------
__global__ __launch_bounds__(256) void qkv_mfma_kernel(
    const bf16* __restrict__ A,
    const bf16* __restrict__ wqt, const bf16* __restrict__ wkt, const bf16* __restrict__ wvt,
    const float* __restrict__ bq, const float* __restrict__ bk, const float* __restrict__ bv,
    float* __restrict__ aexp, float* __restrict__ bexp, bf16* __restrict__ vT)
{
    int z = blockIdx.z;
    const bf16*  Wt   = (z == 0) ? wqt : (z == 1) ? wkt : wvt;
    const float* bias = (z == 0) ? bq  : (z == 1) ? bk  : bv;

    int lane = threadIdx.x & 63, wid = threadIdx.x >> 6;
    int rowBase = blockIdx.y * 32 + (wid >> 1) * 16;
    int colBase = blockIdx.x * 64 + (wid & 1) * 32;

    const bf16* Ap  = A  + (size_t)(rowBase + (lane & 15)) * D_MODEL + ((lane >> 4) << 3);
    const bf16* Bp0 = Wt + (size_t)(colBase + (lane & 15)) * D_MODEL + ((lane >> 4) << 3);
    const bf16* Bp1 = Bp0 + (size_t)16 * D_MODEL;

    f32x4 acc0 = {0.f, 0.f, 0.f, 0.f};
    f32x4 acc1 = {0.f, 0.f, 0.f, 0.f};

    #pragma unroll 4
    for (int k0 = 0; k0 < D_MODEL; k0 += 32) {
        short8 a  = *reinterpret_cast<const short8*>(Ap  + k0);
        short8 b0 = *reinterpret_cast<const short8*>(Bp0 + k0);
        short8 b1 = *reinterpret_cast<const short8*>(Bp1 + k0);
        acc0 = __builtin_amdgcn_mfma_f32_16x16x32_bf16(a, b0, acc0, 0, 0, 0);
        acc1 = __builtin_amdgcn_mfma_f32_16x16x32_bf16(a, b1, acc1, 0, 0, 0);
    }

    int crow = rowBase + ((lane >> 4) << 2);   // rows crow..crow+3
    int ccol = colBase + (lane & 15);          // cols ccol, ccol+16

    if (z < 2) {
        float* C = (z == 0) ? aexp : bexp;
        #pragma unroll
        for (int r = 0; r < 4; ++r) {
            int row = crow + r;
            #pragma unroll
            for (int j = 0; j < 2; ++j) {
                int col = ccol + j * 16;
                float val = (j == 0 ? acc0[r] : acc1[r]) + bias[col];
                C[(size_t)row * D_MODEL + col] = __expf(2.0f * val);
            }
        }
    } else {
        int bb = crow / NSEQ;                  // batch (crow..crow+3 same batch)
        int jr = crow - bb * NSEQ;
        #pragma unroll
        for (int j = 0; j < 2; ++j) {
            int col = ccol + j * 16;
            short4v pk;
            #pragma unroll
            for (int r = 0; r < 4; ++r)
                pk[r] = bfb((j == 0 ? acc0[r] : acc1[r]) + bias[col]);
            size_t idx = ((size_t)bb * D_MODEL + col) * NSEQ + jr;
            *reinterpret_cast<short4v*>((short*)vT + idx) = pk;
        }
    }
}

// ---------------------------------------------------------------------------
// Kernel 4: additive-attention unnormalized weights (round-4 lane layout +
// j-half split + 2-j ILP).
// E[i][j] = exp( sum_d (-2 scale_d) * rcp(a_id*b_jd + 1) )  (row-const cancels;
// |u|<=41 so no max needed).  Sp[i][half] = partial sum over this j-half.
// grid (NROWS/2, 2); 512 thr (8 waves). Wave w: j in {half*192 + w + 8t}.
// Lane l owns d-slice [8l, 8l+8); b-row loads fully coalesced (64 x 32B).
// ---------------------------------------------------------------------------
__global__ __launch_bounds__(512) void score_kernel(
    const float* __restrict__ aexp, const float* __restrict__ bexp,
    const float* __restrict__ scale, bf16* __restrict__ E,
    float* __restrict__ Sp)
{
    int ip   = blockIdx.x;         // i-pair index
    int half = blockIdx.y;         // j-half
    int row0 = ip * 2;
    int b    = row0 / NSEQ;
    int tid  = threadIdx.x;
    int lane = tid & 63, wid = tid >> 6;

    __shared__ float sred[8][2];

    // per-lane fragments (coalesced wave-uniform row loads, L1/L2 hot)
    const float* a0p = aexp + (size_t)row0 * D_MODEL + lane * 8;
    float4 A0 = *(const float4*)(a0p);
    float4 A1 = *(const float4*)(a0p + 4);
    float4 B0 = *(const float4*)(a0p + D_MODEL);
    float4 B1 = *(const float4*)(a0p + D_MODEL + 4);
    const float* sp0 = scale + lane * 8;
    float4 S0 = *(const float4*)(sp0);
    float4 S1 = *(const float4*)(sp0 + 4);
    float a0[8] = {A0.x,A0.y,A0.z,A0.w,A1.x,A1.y,A1.z,A1.w};
    float a1[8] = {B0.x,B0.y,B0.z,B0.w,B1.x,B1.y,B1.z,B1.w};
    float sv[8] = {-2.0f*S0.x,-2.0f*S0.y,-2.0f*S0.z,-2.0f*S0.w,
                   -2.0f*S1.x,-2.0f*S1.y,-2.0f*S1.z,-2.0f*S1.w};

    const float* kb = bexp + (size_t)b * NSEQ * D_MODEL + lane * 8;
    int jb = half * 192 + wid;

    float es0 = 0.0f, es1 = 0.0f;

    for (int t = 0; t < 24; t += 2) {
        int j0 = jb + t * 8;
        int j1 = j0 + 8;
        const float4* kp0 = (const float4*)(kb + (size_t)j0 * D_MODEL);
        const float4* kp1 = (const float4*)(kb + (size_t)j1 * D_MODEL);
        float4 x0v = kp0[0], x1v = kp0[1];
        float4 y0v = kp1[0], y1v = kp1[1];
        float b0[8] = {x0v.x,x0v.y,x0v.z,x0v.w,x1v.x,x1v.y,x1v.z,x1v.w};
        float b1[8] = {y0v.x,y0v.y,y0v.z,y0v.w,y1v.x,y1v.y,y1v.z,y1v.w};

        float t00 = 0.f, t01 = 0.f, t10 = 0.f, t11 = 0.f; // t<row><jslot>
        #pragma unroll
        for (int u = 0; u < 8; ++u) {
            float r0 = __builtin_amdgcn_rcpf(fmaf(a0[u], b0[u], 1.0f));
            float r1 = __builtin_amdgcn_rcpf(fmaf(a1[u], b0[u], 1.0f));
            float r2 = __builtin_amdgcn_rcpf(fmaf(a0[u], b1[u], 1.0f));
            float r3 = __builtin_amdgcn_rcpf(fmaf(a1[u], b1[u], 1.0f));
            t00 = fmaf(sv[u], r0, t00);
            t01 = fmaf(sv[u], r1, t01);
            t10 = fmaf(sv[u], r2, t10);
            t11 = fmaf(sv[u], r3, t11);
        }
        #pragma unroll
        for (int off = 1; off < 64; off <<= 1) {
            t00 += __shfl_xor(t00, off, 64);
            t01 += __shfl_xor(t01, off, 64);
            t10 += __shfl_xor(t10, off, 64);
            t11 += __shfl_xor(t11, off, 64);
        }
        float e00 = __expf(t00);   // row0, j0
        float e01 = __expf(t01);   // row1, j0
        float e10 = __expf(t10);   // row0, j1
        float e11 = __expf(t11);   // row1, j1
        if (lane == 0) {
            E[(size_t)row0 * NSEQ + j0]       = __float2bfloat16(e00);
            E[(size_t)(row0 + 1) * NSEQ + j0] = __float2bfloat16(e01);
            E[(size_t)row0 * NSEQ + j1]       = __float2bfloat16(e10);
            E[(size_t)(row0 + 1) * NSEQ + j1] = __float2bfloat16(e11);
        }
        es0 += e00 + e10;
        es1 += e01 + e11;
    }

    // es identical on all lanes (post-butterfly); lane 0 publishes per-wave sum
    if (lane == 0) { sred[wid][0] = es0; sred[wid][1] = es1; }
    __syncthreads();
    if (tid < 2) {
        float s = 0.0f;
        #pragma unroll
        for (int w = 0; w < 8; ++w) s += sred[w][tid];
        Sp[(size_t)(row0 + tid) * 2 + half] = s;
    }
}

// ---------------------------------------------------------------------------
// Kernel 5: PV MFMA + normalize: attnb[b,i,d] = (sum_j E[b,i,j] v[b,j,d]) / S_i
// ---------------------------------------------------------------------------
__global__ __launch_bounds__(256) void pv_mfma_kernel(
    const bf16* __restrict__ E, const bf16* __restrict__ vT,
    const float* __restrict__ Sp, bf16* __restrict__ attnb)
{
    int z = blockIdx.z;
    int lane = threadIdx.x & 63, wid = threadIdx.x >> 6;
    int rowBase = blockIdx.y * 32 + (wid >> 1) * 16;
    int colBase = blockIdx.x * 64 + (wid & 1) * 32;

    const bf16* Ap  = E  + ((size_t)z * NSEQ + rowBase + (lane & 15)) * NSEQ + ((lane >> 4) << 3);
    const bf16* Bp0 = vT + ((size_t)z * D_MODEL + colBase + (lane & 15)) * NSEQ + ((lane >> 4) << 3);
    const bf16* Bp1 = Bp0 + (size_t)16 * NSEQ;

    f32x4 acc0 = {0.f, 0.f, 0.f, 0.f};
    f32x4 acc1 = {0.f, 0.f, 0.f, 0.f};

    #pragma unroll 4
    for (int k0 = 0; k0 < NSEQ; k0 += 32) {
        short8 a  = *reinterpret_cast<const short8*>(Ap  + k0);
        short8 b0 = *reinterpret_cast<const short8*>(Bp0 + k0);
        short8 b1 = *reinterpret_cast<const short8*>(Bp1 + k0);
        acc0 = __builtin_amdgcn_mfma_f32_16x16x32_bf16(a, b0, acc0, 0, 0, 0);
        acc1 = __builtin_amdgcn_mfma_f32_16x16x32_bf16(a, b1, acc1, 0, 0, 0);
    }

    int crow = rowBase + ((lane >> 4) << 2);
    int ccol = colBase + (lane & 15);
    #pragma unroll
    for (int r = 0; r < 4; ++r) {
        int grow = z * NSEQ + crow + r;
        float Sinv = 1.0f / (Sp[(size_t)grow * 2] + Sp[(size_t)grow * 2 + 1]);
        #pragma unroll
        for (int j = 0; j < 2; ++j)
            attnb[(size_t)grow * D_MODEL + ccol + j * 16] =
                __float2bfloat16((j == 0 ? acc0[r] : acc1[r]) * Sinv);
    }
}

// ---------------------------------------------------------------------------
// Kernel 6: generic bf16 MFMA GEMM (no LDS): C = A @ Wt^T + bias (+resid)(+relu)
// ---------------------------------------------------------------------------
__global__ __launch_bounds__(256) void mfma_gemm_kernel(
    const bf16* __restrict__ A, const bf16* __restrict__ Wt,
    const float* __restrict__ bias, const float* __restrict__ resid,
    float* __restrict__ Cf, bf16* __restrict__ Cb,
    int K, int N, int relu)
{
    int lane = threadIdx.x & 63, wid = threadIdx.x >> 6;
    int rowBase = blockIdx.y * 32 + (wid >> 1) * 16;
    int colBase = blockIdx.x * 64 + (wid & 1) * 32;

    const bf16* Ap  = A  + (size_t)(rowBase + (lane & 15)) * K + ((lane >> 4) << 3);
    const bf16* Bp0 = Wt + (size_t)(colBase + (lane & 15)) * K + ((lane >> 4) << 3);
    const bf16* Bp1 = Bp0 + (size_t)16 * K;

    f32x4 acc0 = {0.f, 0.f, 0.f, 0.f};
    f32x4 acc1 = {0.f, 0.f, 0.f, 0.f};

    #pragma unroll 4
    for (int k0 = 0; k0 < K; k0 += 32) {
        short8 a  = *reinterpret_cast<const short8*>(Ap  + k0);
        short8 b0 = *reinterpret_cast<const short8*>(Bp0 + k0);
        short8 b1 = *reinterpret_cast<const short8*>(Bp1 + k0);
        acc0 = __builtin_amdgcn_mfma_f32_16x16x32_bf16(a, b0, acc0, 0, 0, 0);
        acc1 = __builtin_amdgcn_mfma_f32_16x16x32_bf16(a, b1, acc1, 0, 0, 0);
    }

    int crow = rowBase + ((lane >> 4) << 2);
    int ccol = colBase + (lane & 15);
    #pragma unroll
    for (int r = 0; r < 4; ++r) {
        int row = crow + r;
        #pragma unroll
        for (int j = 0; j < 2; ++j) {
            int col = ccol + j * 16;
            float val = (j == 0 ? acc0[r] : acc1[r]) + bias[col];
            if (resid) val += resid[(size_t)row * N + col];
            if (relu)  val = fmaxf(val, 0.0f);
            if (Cf) Cf[(size_t)row * N + col] = val;
            if (Cb) Cb[(size_t)row * N + col] = __float2bfloat16(val);
        }
    }
}

// ---------------------------------------------------------------------------
// Kernel 7: LayerNorm over last dim (512); optional bf16 shadow output
// ---------------------------------------------------------------------------
__global__ __launch_bounds__(256) void ln_kernel(
    const float* __restrict__ in, const float* __restrict__ gamma,
    const float* __restrict__ beta, float* __restrict__ out,
    bf16* __restrict__ outb)
{
    int row = blockIdx.x;
    int tid = threadIdx.x;
    int lane = tid & 63, wid = tid >> 6;
    __shared__ float red[4];

    float v0 = in[(size_t)row * D_MODEL + tid];
    float v1 = in[(size_t)row * D_MODEL + tid + 256];

    float s = v0 + v1;
    #pragma unroll
    for (int off = 32; off; off >>= 1) s += __shfl_xor(s, off, 64);
    if (lane == 0) red[wid] = s;
    __syncthreads();
    if (tid == 0) red[0] = red[0] + red[1] + red[2] + red[3];
    __syncthreads();
    float mu = red[0] * (1.0f / D_MODEL);
    __syncthreads();

    float d0 = v0 - mu, d1 = v1 - mu;
    float s2 = d0 * d0 + d1 * d1;
    #pragma unroll
    for (int off = 32; off; off >>= 1) s2 += __shfl_xor(s2, off, 64);
    if (lane == 0) red[wid] = s2;
    __syncthreads();
    if (tid == 0) red[0] = red[0] + red[1] + red[2] + red[3];
    __syncthreads();
    float var = red[0] * (1.0f / D_MODEL);
    float inv = rsqrtf(var + LN_EPS);

    float o0 = d0 * inv * gamma[tid] + beta[tid];
    float o1 = d1 * inv * gamma[tid + 256] + beta[tid + 256];
    out[(size_t)row * D_MODEL + tid]       = o0;
    out[(size_t)row * D_MODEL + tid + 256] = o1;
    if (outb) {
        outb[(size_t)row * D_MODEL + tid]       = __float2bfloat16(o0);
        outb[(size_t)row * D_MODEL + tid + 256] = __float2bfloat16(o1);
    }
}

// ---------------------------------------------------------------------------
extern "C" void kernel_launch(void* const* d_in, const int* in_sizes, int n_in,
                              void* d_out, int out_size, void* d_ws, size_t ws_size,
                              hipStream_t stream)
{
    const int*   tokens = (const int*)  d_in[0];
    const float* emb    = (const float*)d_in[1];
    const float* Wq     = (const float*)d_in[2];
    const float* bq     = (const float*)d_in[3];
    const float* Wk     = (const float*)d_in[4];
    const float* bk     = (const float*)d_in[5];
    const float* Wv     = (const float*)d_in[6];
    const float* bv     = (const float*)d_in[7];
    const float* ascale = (const float*)d_in[8];
    const float* Wo     = (const float*)d_in[9];
    const float* bo     = (const float*)d_in[10];
    const float* g1     = (const float*)d_in[11];
    const float* beta1  = (const float*)d_in[12];
    const float* W1     = (const float*)d_in[13];
    const float* bf1    = (const float*)d_in[14];
    const float* W2     = (const float*)d_in[15];
    const float* bf2    = (const float*)d_in[16];
    const float* g2     = (const float*)d_in[17];
    const float* beta2  = (const float*)d_in[18];

    float* out = (float*)d_out;
    float* ws  = (float*)d_ws;

    const size_t SZ = (size_t)NROWS * D_MODEL;   // 393216

    float* x0   = ws;            // live until Wo residual
    float* aexp = ws + 1 * SZ;   // exp(2q); dead after score -> reuse as t1
    float* bexp = ws + 2 * SZ;   // exp(2k); dead after score -> reuse as x1
    float* t1 = aexp;
    float* x1 = bexp;
    float* y  = x0;              // x0 dead after Wo

    bf16* x0b   = (bf16*)(ws + 3 * SZ);
    bf16* attnb = x0b + SZ;
    bf16* x1b   = attnb + SZ;
    bf16* hb    = x1b + SZ;                          // NROWS * D_FF
    bf16* Eb    = hb + (size_t)NROWS * D_FF;         // 2*384*384
    bf16* vTb   = Eb + (size_t)NBATCH * NSEQ * NSEQ; // 2*512*384
    bf16* wqt   = vTb + (size_t)NBATCH * D_MODEL * NSEQ;
    bf16* wkt   = wqt + (size_t)D_MODEL * D_MODEL;
    bf16* wvt   = wkt + (size_t)D_MODEL * D_MODEL;
    bf16* wot   = wvt + (size_t)D_MODEL * D_MODEL;
    bf16* w1t   = wot + (size_t)D_MODEL * D_MODEL;   // [D_FF][D_MODEL]
    bf16* w2t   = w1t + (size_t)D_MODEL * D_FF;      // [D_MODEL][D_FF]
    float* Sp   = (float*)(w2t + (size_t)D_FF * D_MODEL);  // [NROWS][2]

    // 1. all weight transposes (one dispatch)
    wt_all_kernel<<<3072, 256, 0, stream>>>(Wq, Wk, Wv, Wo, W1, W2,
                                            wqt, wkt, wvt, wot, w1t, w2t);

    // 2. embedding + positional encoding
    embed_pe_kernel<<<NROWS, 256, 0, stream>>>(tokens, emb, x0, x0b);

    // 3. fused QKV (z: 0->aexp, 1->bexp, 2->vT bf16)
    qkv_mfma_kernel<<<dim3(D_MODEL / 64, NROWS / 32, 3), 256, 0, stream>>>(
        x0b, wqt, wkt, wvt, bq, bk, bv, aexp, bexp, vTb);

    // 4. unnormalized attention weights E + partial row-sums Sp
    score_kernel<<<dim3(NROWS / 2, 2), 512, 0, stream>>>(aexp, bexp, ascale, Eb, Sp);

    // 5. PV + normalize -> attnb bf16
    pv_mfma_kernel<<<dim3(D_MODEL / 64, NSEQ / 32, NBATCH), 256, 0, stream>>>(
        Eb, vTb, Sp, attnb);

    // 6. output projection + residual -> t1 f32
    mfma_gemm_kernel<<<dim3(D_MODEL / 64, NROWS / 32), 256, 0, stream>>>(
        attnb, wot, bo, x0, t1, nullptr, D_MODEL, D_MODEL, 0);

    // 7. LayerNorm 1 -> x1 f32 + x1b bf16
    ln_kernel<<<NROWS, 256, 0, stream>>>(t1, g1, beta1, x1, x1b);

    // 8. FF up + ReLU -> hb bf16
    mfma_gemm_kernel<<<dim3(D_FF / 64, NROWS / 32), 256, 0, stream>>>(
        x1b, w1t, bf1, nullptr, nullptr, hb, D_MODEL, D_FF, 1);

    // 9. FF down + residual -> y f32
    mfma_gemm_kernel<<<dim3(D_MODEL / 64, NROWS / 32), 256, 0, stream>>>(
        hb, w2t, bf2, x1, y, nullptr, D_FF, D_MODEL, 0);

    // 10. LayerNorm 2 -> out
    ln_kernel<<<NROWS, 256, 0, stream>>>(y, g2, beta2, out, nullptr);
}

// Round 8
// 125.806 us; speedup vs baseline: 1.4893x; 1.0324x over previous
//
#include <hip/hip_runtime.h>
#include <hip/hip_bf16.h>
#include <math.h>

#define D_MODEL 512
#define D_FF    2048
#define NBATCH  2
#define NSEQ    384
#define NROWS   (NBATCH * NSEQ)
#define LN_EPS  1e-6f

typedef __attribute__((ext_vector_type(8))) short short8;
typedef __attribute__((ext_vector_type(4))) short short4v;
typedef __attribute__((ext_vector_type(4))) float f32x4;
typedef __hip_bfloat16 bf16;

static __device__ __forceinline__ short bfb(float x) {
    bf16 h = __float2bfloat16(x);
    return *reinterpret_cast<short*>(&h);
}

// ---------------------------------------------------------------------------
// Kernel 1: fused prep. Blocks 0..3071: weight transpose W[K][N]f32->Wt[N][K]bf16.
// Blocks 3072..3839: embed+PE row (fast native trig).
// ---------------------------------------------------------------------------
__global__ __launch_bounds__(256) void prep_kernel(
    const int* __restrict__ tokens, const float* __restrict__ emb,
    const float* __restrict__ Wq, const float* __restrict__ Wk,
    const float* __restrict__ Wv, const float* __restrict__ Wo,
    const float* __restrict__ W1, const float* __restrict__ W2,
    bf16* __restrict__ wqt, bf16* __restrict__ wkt, bf16* __restrict__ wvt,
    bf16* __restrict__ wot, bf16* __restrict__ w1t, bf16* __restrict__ w2t,
    float* __restrict__ x, bf16* __restrict__ xb)
{
    __shared__ float tile[32][33];
    int t = blockIdx.x;

    if (t < 3072) {
        const float* W; bf16* Wt; int K, N, bx, by;
        if (t < 1024) {
            int w = t >> 8, rem = t & 255;
            W  = (w == 0) ? Wq  : (w == 1) ? Wk  : (w == 2) ? Wv  : Wo;
            Wt = (w == 0) ? wqt : (w == 1) ? wkt : (w == 2) ? wvt : wot;
            K = 512; N = 512; bx = rem & 15; by = rem >> 4;
        } else if (t < 2048) {
            int rem = t - 1024;
            W = W1; Wt = w1t; K = 512; N = 2048; bx = rem & 63; by = rem >> 6;
        } else {
            int rem = t - 2048;
            W = W2; Wt = w2t; K = 2048; N = 512; bx = rem & 15; by = rem >> 4;
        }
        int tx = threadIdx.x & 31, ty = threadIdx.x >> 5;
        #pragma unroll
        for (int r = ty; r < 32; r += 8)
            tile[r][tx] = W[(size_t)(by * 32 + r) * N + bx * 32 + tx];
        __syncthreads();
        #pragma unroll
        for (int r = ty; r < 32; r += 8)
            Wt[(size_t)(bx * 32 + r) * K + by * 32 + tx] = __float2bfloat16(tile[tx][r]);
    } else {
        int row = t - 3072;              // b*NSEQ + n
        int n   = row % NSEQ;
        int tok = tokens[row];
        const float sqrtD = 22.627416997969522f; // sqrt(512)
        const float ESC   = 0.02595256324130752f; // log2(10000)/512
        for (int d = threadIdx.x; d < D_MODEL; d += 256) {
            float e   = emb[tok * D_MODEL + d] * sqrtD;
            float ang = (float)n * __builtin_amdgcn_exp2f(-(float)(d & ~1) * ESC);
            float pe  = (d & 1) ? __cosf(ang) : __sinf(ang);
            float val = e + pe;
            x [(size_t)row * D_MODEL + d] = val;
            xb[(size_t)row * D_MODEL + d] = __float2bfloat16(val);
        }
    }
}

// ---------------------------------------------------------------------------
// Kernel 2: fused QKV MFMA GEMM (no LDS). blockIdx.z selects q/k/v.
//  z=0: aexp = exp(2*(x@Wq+bq))   f32
//  z=1: bexp = exp(2*(x@Wk+bk))   f32
//  z=2: vT[b][d][j] = bf16(x@Wv+bv)   (transposed for PV MFMA B-operand)
// ---------------------------------------------------------------------------
__global__ __launch_bounds__(256) void qkv_mfma_kernel(
    const bf16* __restrict__ A,
    const bf16* __restrict__ wqt, const bf16* __restrict__ wkt, const bf16* __restrict__ wvt,
    const float* __restrict__ bq, const float* __restrict__ bk, const float* __restrict__ bv,
    float* __restrict__ aexp, float* __restrict__ bexp, bf16* __restrict__ vT)
{
    int z = blockIdx.z;
    const bf16*  Wt   = (z == 0) ? wqt : (z == 1) ? wkt : wvt;
    const float* bias = (z == 0) ? bq  : (z == 1) ? bk  : bv;

    int lane = threadIdx.x & 63, wid = threadIdx.x >> 6;
    int rowBase = blockIdx.y * 32 + (wid >> 1) * 16;
    int colBase = blockIdx.x * 64 + (wid & 1) * 32;

    const bf16* Ap  = A  + (size_t)(rowBase + (lane & 15)) * D_MODEL + ((lane >> 4) << 3);
    const bf16* Bp0 = Wt + (size_t)(colBase + (lane & 15)) * D_MODEL + ((lane >> 4) << 3);
    const bf16* Bp1 = Bp0 + (size_t)16 * D_MODEL;

    f32x4 acc0 = {0.f, 0.f, 0.f, 0.f};
    f32x4 acc1 = {0.f, 0.f, 0.f, 0.f};

    #pragma unroll 4
    for (int k0 = 0; k0 < D_MODEL; k0 += 32) {
        short8 a  = *reinterpret_cast<const short8*>(Ap  + k0);
        short8 b0 = *reinterpret_cast<const short8*>(Bp0 + k0);
        short8 b1 = *reinterpret_cast<const short8*>(Bp1 + k0);
        acc0 = __builtin_amdgcn_mfma_f32_16x16x32_bf16(a, b0, acc0, 0, 0, 0);
        acc1 = __builtin_amdgcn_mfma_f32_16x16x32_bf16(a, b1, acc1, 0, 0, 0);
    }

    int crow = rowBase + ((lane >> 4) << 2);   // rows crow..crow+3
    int ccol = colBase + (lane & 15);          // cols ccol, ccol+16

    if (z < 2) {
        float* C = (z == 0) ? aexp : bexp;
        #pragma unroll
        for (int r = 0; r < 4; ++r) {
            int row = crow + r;
            #pragma unroll
            for (int j = 0; j < 2; ++j) {
                int col = ccol + j * 16;
                float val = (j == 0 ? acc0[r] : acc1[r]) + bias[col];
                C[(size_t)row * D_MODEL + col] = __expf(2.0f * val);
            }
        }
    } else {
        int bb = crow / NSEQ;                  // batch (crow..crow+3 same batch)
        int jr = crow - bb * NSEQ;
        #pragma unroll
        for (int j = 0; j < 2; ++j) {
            int col = ccol + j * 16;
            short4v pk;
            #pragma unroll
            for (int r = 0; r < 4; ++r)
                pk[r] = bfb((j == 0 ? acc0[r] : acc1[r]) + bias[col]);
            size_t idx = ((size_t)bb * D_MODEL + col) * NSEQ + jr;
            *reinterpret_cast<short4v*>((short*)vT + idx) = pk;
        }
    }
}

// ---------------------------------------------------------------------------
// Kernel 3: additive-attention unnormalized weights.
// u_ij = sum_d sv_d * rcp(a_id*b_jd + 1), sv = -2*scale (row-const cancels in
// softmax; |u|<=41 so exp never overflows). Pairwise-rcp: for d-pair (x,y):
//   sv0/p + sv1/q = (sv0*q + sv1*p) * rcp(p*q),  p=a0*x+1, q=a1*y+1
// E = exp(u) bf16 (unnormalized); Sp[row][quarter] = partial sums.
// grid (NROWS/4, 4); 512 thr (8 waves). 4 i-rows per block, 96 j's per block.
// Lane l owns d-slice [8l,8l+8); b-loads coalesced (64 lanes x 32B = row).
// ---------------------------------------------------------------------------
__global__ __launch_bounds__(512) void score_kernel(
    const float* __restrict__ aexp, const float* __restrict__ bexp,
    const float* __restrict__ scale, bf16* __restrict__ E,
    float* __restrict__ Sp)
{
    int ig   = blockIdx.x;         // i-group of 4 rows
    int qt   = blockIdx.y;         // j-quarter
    int row0 = ig * 4;
    int b    = row0 / NSEQ;
    int tid  = threadIdx.x;
    int lane = tid & 63, wid = tid >> 6;

    __shared__ float sred[8][4];

    // per-lane fragments: 4 i-rows of a, plus sv (coalesced row loads)
    const float* ap = aexp + (size_t)row0 * D_MODEL + lane * 8;
    float a[4][8];
    #pragma unroll
    for (int r = 0; r < 4; ++r) {
        float4 A0 = *(const float4*)(ap + (size_t)r * D_MODEL);
        float4 A1 = *(const float4*)(ap + (size_t)r * D_MODEL + 4);
        a[r][0]=A0.x; a[r][1]=A0.y; a[r][2]=A0.z; a[r][3]=A0.w;
        a[r][4]=A1.x; a[r][5]=A1.y; a[r][6]=A1.z; a[r][7]=A1.w;
    }
    float4 S0 = *(const float4*)(scale + lane * 8);
    float4 S1 = *(const float4*)(scale + lane * 8 + 4);
    float sv[8] = {-2.0f*S0.x,-2.0f*S0.y,-2.0f*S0.z,-2.0f*S0.w,
                   -2.0f*S1.x,-2.0f*S1.y,-2.0f*S1.z,-2.0f*S1.w};

    const float* kb = bexp + (size_t)b * NSEQ * D_MODEL + lane * 8;
    int jb = qt * 96 + wid;

    float es[4] = {0.f, 0.f, 0.f, 0.f};

    for (int t6 = 0; t6 < 6; ++t6) {
        int j0 = jb + t6 * 16;
        int j1 = j0 + 8;
        const float4* kp0 = (const float4*)(kb + (size_t)j0 * D_MODEL);
        const float4* kp1 = (const float4*)(kb + (size_t)j1 * D_MODEL);
        float4 xa = kp0[0], xc = kp0[1];
        float4 ya = kp1[0], yc = kp1[1];
        float b0[8] = {xa.x,xa.y,xa.z,xa.w,xc.x,xc.y,xc.z,xc.w};
        float b1[8] = {ya.x,ya.y,ya.z,ya.w,yc.x,yc.y,yc.z,yc.w};

        float u[4][2] = {};
        #pragma unroll
        for (int up = 0; up < 4; ++up) {
            int d0 = up * 2, d1 = d0 + 1;
            #pragma unroll
            for (int js = 0; js < 2; ++js) {
                float xx = js ? b1[d0] : b0[d0];
                float yy = js ? b1[d1] : b0[d1];
                #pragma unroll
                for (int r = 0; r < 4; ++r) {
                    float p   = fmaf(a[r][d0], xx, 1.0f);
                    float q   = fmaf(a[r][d1], yy, 1.0f);
                    float num = fmaf(sv[d0], q, sv[d1] * p);
                    u[r][js]  = fmaf(num, __builtin_amdgcn_rcpf(p * q), u[r][js]);
                }
            }
        }

        #pragma unroll
        for (int off = 1; off < 64; off <<= 1) {
            #pragma unroll
            for (int r = 0; r < 4; ++r) {
                u[r][0] += __shfl_xor(u[r][0], off, 64);
                u[r][1] += __shfl_xor(u[r][1], off, 64);
            }
        }

        #pragma unroll
        for (int r = 0; r < 4; ++r) {
            float e0 = __expf(u[r][0]);
            float e1 = __expf(u[r][1]);
            if (lane == 0) {
                E[(size_t)(row0 + r) * NSEQ + j0] = __float2bfloat16(e0);
                E[(size_t)(row0 + r) * NSEQ + j1] = __float2bfloat16(e1);
            }
            es[r] += e0 + e1;
        }
    }

    if (lane == 0) {
        sred[wid][0] = es[0]; sred[wid][1] = es[1];
        sred[wid][2] = es[2]; sred[wid][3] = es[3];
    }
    __syncthreads();
    if (tid < 4) {
        float s = 0.0f;
        #pragma unroll
        for (int w = 0; w < 8; ++w) s += sred[w][tid];
        Sp[(size_t)(row0 + tid) * 4 + qt] = s;
    }
}

// ---------------------------------------------------------------------------
// Kernel 4: PV MFMA + normalize: attnb[b,i,d] = (sum_j E[b,i,j] v[b,j,d]) / S_i
// ---------------------------------------------------------------------------
__global__ __launch_bounds__(256) void pv_mfma_kernel(
    const bf16* __restrict__ E, const bf16* __restrict__ vT,
    const float* __restrict__ Sp, bf16* __restrict__ attnb)
{
    int z = blockIdx.z;
    int lane = threadIdx.x & 63, wid = threadIdx.x >> 6;
    int rowBase = blockIdx.y * 32 + (wid >> 1) * 16;
    int colBase = blockIdx.x * 64 + (wid & 1) * 32;

    const bf16* Ap  = E  + ((size_t)z * NSEQ + rowBase + (lane & 15)) * NSEQ + ((lane >> 4) << 3);
    const bf16* Bp0 = vT + ((size_t)z * D_MODEL + colBase + (lane & 15)) * NSEQ + ((lane >> 4) << 3);
    const bf16* Bp1 = Bp0 + (size_t)16 * NSEQ;

    f32x4 acc0 = {0.f, 0.f, 0.f, 0.f};
    f32x4 acc1 = {0.f, 0.f, 0.f, 0.f};

    #pragma unroll 4
    for (int k0 = 0; k0 < NSEQ; k0 += 32) {
        short8 a  = *reinterpret_cast<const short8*>(Ap  + k0);
        short8 b0 = *reinterpret_cast<const short8*>(Bp0 + k0);
        short8 b1 = *reinterpret_cast<const short8*>(Bp1 + k0);
        acc0 = __builtin_amdgcn_mfma_f32_16x16x32_bf16(a, b0, acc0, 0, 0, 0);
        acc1 = __builtin_amdgcn_mfma_f32_16x16x32_bf16(a, b1, acc1, 0, 0, 0);
    }

    int crow = rowBase + ((lane >> 4) << 2);
    int ccol = colBase + (lane & 15);
    #pragma unroll
    for (int r = 0; r < 4; ++r) {
        int grow = z * NSEQ + crow + r;
        float4 sp4 = *(const float4*)(Sp + (size_t)grow * 4);
        float Sinv = 1.0f / (sp4.x + sp4.y + sp4.z + sp4.w);
        #pragma unroll
        for (int j = 0; j < 2; ++j)
            attnb[(size_t)grow * D_MODEL + ccol + j * 16] =
                __float2bfloat16((j == 0 ? acc0[r] : acc1[r]) * Sinv);
    }
}

// ---------------------------------------------------------------------------
// Kernel 5: generic bf16 MFMA GEMM (no LDS): C = A @ Wt^T + bias (+resid)(+relu)
// ---------------------------------------------------------------------------
__global__ __launch_bounds__(256) void mfma_gemm_kernel(
    const bf16* __restrict__ A, const bf16* __restrict__ Wt,
    const float* __restrict__ bias, const float* __restrict__ resid,
    float* __restrict__ Cf, bf16* __restrict__ Cb,
    int K, int N, int relu)
{
    int lane = threadIdx.x & 63, wid = threadIdx.x >> 6;
    int rowBase = blockIdx.y * 32 + (wid >> 1) * 16;
    int colBase = blockIdx.x * 64 + (wid & 1) * 32;

    const bf16* Ap  = A  + (size_t)(rowBase + (lane & 15)) * K + ((lane >> 4) << 3);
    const bf16* Bp0 = Wt + (size_t)(colBase + (lane & 15)) * K + ((lane >> 4) << 3);
    const bf16* Bp1 = Bp0 + (size_t)16 * K;

    f32x4 acc0 = {0.f, 0.f, 0.f, 0.f};
    f32x4 acc1 = {0.f, 0.f, 0.f, 0.f};

    #pragma unroll 4
    for (int k0 = 0; k0 < K; k0 += 32) {
        short8 a  = *reinterpret_cast<const short8*>(Ap  + k0);
        short8 b0 = *reinterpret_cast<const short8*>(Bp0 + k0);
        short8 b1 = *reinterpret_cast<const short8*>(Bp1 + k0);
        acc0 = __builtin_amdgcn_mfma_f32_16x16x32_bf16(a, b0, acc0, 0, 0, 0);
        acc1 = __builtin_amdgcn_mfma_f32_16x16x32_bf16(a, b1, acc1, 0, 0, 0);
    }

    int crow = rowBase + ((lane >> 4) << 2);
    int ccol = colBase + (lane & 15);
    #pragma unroll
    for (int r = 0; r < 4; ++r) {
        int row = crow + r;
        #pragma unroll
        for (int j = 0; j < 2; ++j) {
            int col = ccol + j * 16;
            float val = (j == 0 ? acc0[r] : acc1[r]) + bias[col];
            if (resid) val += resid[(size_t)row * N + col];
            if (relu)  val = fmaxf(val, 0.0f);
            if (Cf) Cf[(size_t)row * N + col] = val;
            if (Cb) Cb[(size_t)row * N + col] = __float2bfloat16(val);
        }
    }
}

// ---------------------------------------------------------------------------
// Kernel 6: LayerNorm over last dim (512); optional bf16 shadow output
// ---------------------------------------------------------------------------
__global__ __launch_bounds__(256) void ln_kernel(
    const float* __restrict__ in, const float* __restrict__ gamma,
    const float* __restrict__ beta, float* __restrict__ out,
    bf16* __restrict__ outb)
{
    int row = blockIdx.x;
    int tid = threadIdx.x;
    int lane = tid & 63, wid = tid >> 6;
    __shared__ float red[4];

    float v0 = in[(size_t)row * D_MODEL + tid];
    float v1 = in[(size_t)row * D_MODEL + tid + 256];

    float s = v0 + v1;
    #pragma unroll
    for (int off = 32; off; off >>= 1) s += __shfl_xor(s, off, 64);
    if (lane == 0) red[wid] = s;
    __syncthreads();
    if (tid == 0) red[0] = red[0] + red[1] + red[2] + red[3];
    __syncthreads();
    float mu = red[0] * (1.0f / D_MODEL);
    __syncthreads();

    float d0 = v0 - mu, d1 = v1 - mu;
    float s2 = d0 * d0 + d1 * d1;
    #pragma unroll
    for (int off = 32; off; off >>= 1) s2 += __shfl_xor(s2, off, 64);
    if (lane == 0) red[wid] = s2;
    __syncthreads();
    if (tid == 0) red[0] = red[0] + red[1] + red[2] + red[3];
    __syncthreads();
    float var = red[0] * (1.0f / D_MODEL);
    float inv = rsqrtf(var + LN_EPS);

    float o0 = d0 * inv * gamma[tid] + beta[tid];
    float o1 = d1 * inv * gamma[tid + 256] + beta[tid + 256];
    out[(size_t)row * D_MODEL + tid]       = o0;
    out[(size_t)row * D_MODEL + tid + 256] = o1;
    if (outb) {
        outb[(size_t)row * D_MODEL + tid]       = __float2bfloat16(o0);
        outb[(size_t)row * D_MODEL + tid + 256] = __float2bfloat16(o1);
    }
}

// ---------------------------------------------------------------------------
extern "C" void kernel_launch(void* const* d_in, const int* in_sizes, int n_in,
                              void* d_out, int out_size, void* d_ws, size_t ws_size,
                              hipStream_t stream)
{
    const int*   tokens = (const int*)  d_in[0];
    const float* emb    = (const float*)d_in[1];
    const float* Wq     = (const float*)d_in[2];
    const float* bq     = (const float*)d_in[3];
    const float* Wk     = (const float*)d_in[4];
    const float* bk     = (const float*)d_in[5];
    const float* Wv     = (const float*)d_in[6];
    const float* bv     = (const float*)d_in[7];
    const float* ascale = (const float*)d_in[8];
    const float* Wo     = (const float*)d_in[9];
    const float* bo     = (const float*)d_in[10];
    const float* g1     = (const float*)d_in[11];
    const float* beta1  = (const float*)d_in[12];
    const float* W1     = (const float*)d_in[13];
    const float* bf1    = (const float*)d_in[14];
    const float* W2     = (const float*)d_in[15];
    const float* bf2    = (const float*)d_in[16];
    const float* g2     = (const float*)d_in[17];
    const float* beta2  = (const float*)d_in[18];

    float* out = (float*)d_out;
    float* ws  = (float*)d_ws;

    const size_t SZ = (size_t)NROWS * D_MODEL;   // 393216

    float* x0   = ws;            // live until Wo residual
    float* aexp = ws + 1 * SZ;   // exp(2q); dead after score -> reuse as t1
    float* bexp = ws + 2 * SZ;   // exp(2k); dead after score -> reuse as x1
    float* t1 = aexp;
    float* x1 = bexp;
    float* y  = x0;              // x0 dead after Wo

    bf16* x0b   = (bf16*)(ws + 3 * SZ);
    bf16* attnb = x0b + SZ;
    bf16* x1b   = attnb + SZ;
    bf16* hb    = x1b + SZ;                          // NROWS * D_FF
    bf16* Eb    = hb + (size_t)NROWS * D_FF;         // 2*384*384
    bf16* vTb   = Eb + (size_t)NBATCH * NSEQ * NSEQ; // 2*512*384
    bf16* wqt   = vTb + (size_t)NBATCH * D_MODEL * NSEQ;
    bf16* wkt   = wqt + (size_t)D_MODEL * D_MODEL;
    bf16* wvt   = wkt + (size_t)D_MODEL * D_MODEL;
    bf16* wot   = wvt + (size_t)D_MODEL * D_MODEL;
    bf16* w1t   = wot + (size_t)D_MODEL * D_MODEL;   // [D_FF][D_MODEL]
    bf16* w2t   = w1t + (size_t)D_MODEL * D_FF;      // [D_MODEL][D_FF]
    float* Sp   = (float*)(w2t + (size_t)D_FF * D_MODEL);  // [NROWS][4]

    // 1. weight transposes + embed/PE (one dispatch)
    prep_kernel<<<3072 + NROWS, 256, 0, stream>>>(
        tokens, emb, Wq, Wk, Wv, Wo, W1, W2,
        wqt, wkt, wvt, wot, w1t, w2t, x0, x0b);

    // 2. fused QKV (z: 0->aexp, 1->bexp, 2->vT bf16)
    qkv_mfma_kernel<<<dim3(D_MODEL / 64, NROWS / 32, 3), 256, 0, stream>>>(
        x0b, wqt, wkt, wvt, bq, bk, bv, aexp, bexp, vTb);

    // 3. unnormalized attention weights E + partial row-sums Sp
    score_kernel<<<dim3(NROWS / 4, 4), 512, 0, stream>>>(aexp, bexp, ascale, Eb, Sp);

    // 4. PV + normalize -> attnb bf16
    pv_mfma_kernel<<<dim3(D_MODEL / 64, NSEQ / 32, NBATCH), 256, 0, stream>>>(
        Eb, vTb, Sp, attnb);

    // 5. output projection + residual -> t1 f32
    mfma_gemm_kernel<<<dim3(D_MODEL / 64, NROWS / 32), 256, 0, stream>>>(
        attnb, wot, bo, x0, t1, nullptr, D_MODEL, D_MODEL, 0);

    // 6. LayerNorm 1 -> x1 f32 + x1b bf16
    ln_kernel<<<NROWS, 256, 0, stream>>>(t1, g1, beta1, x1, x1b);

    // 7. FF up + ReLU -> hb bf16
    mfma_gemm_kernel<<<dim3(D_FF / 64, NROWS / 32), 256, 0, stream>>>(
        x1b, w1t, bf1, nullptr, nullptr, hb, D_MODEL, D_FF, 1);

    // 8. FF down + residual -> y f32
    mfma_gemm_kernel<<<dim3(D_MODEL / 64, NROWS / 32), 256, 0, stream>>>(
        hb, w2t, bf2, x1, y, nullptr, D_FF, D_MODEL, 0);

    // 9. LayerNorm 2 -> out
    ln_kernel<<<NROWS, 256, 0, stream>>>(y, g2, beta2, out, nullptr);
}